// Round 1
// baseline (329.081 us; speedup 1.0000x reference)
//
#include <hip/hip_runtime.h>
#include <hip/hip_bf16.h>

// DiffAttention on MI355X: bf16 MFMA pipeline.
// Stages: cvt(f32->bf16) -> gemm_bt x3 (Q,K,V) -> flash attn (per component head)
//         -> combine (O1 - lam*O2, RMSNorm) -> gemm_bt (fp32 out).
// Workspace layout (bytes):
//   xb   @ 0      8MB   (x bf16, 4096x1024)           [reused later for Oc]
//   Wqb  @ 8M     2MB   Wkb @10M  Wvb @12M  Wob @14M
//   Qb   @16M     8MB   Kb @24M   Vb @32M   (each 4096x1024 bf16)
//   Op   @40M    16MB   (O^T per component head: (B,16,128,S) bf16)
//   Oc   @ 0      8MB   (combined (B,S,1024) bf16, reuses xb region)

typedef unsigned short ushort_t;
typedef short short8 __attribute__((ext_vector_type(8)));
typedef unsigned short ushort8v __attribute__((ext_vector_type(8)));
typedef unsigned short ushort4v __attribute__((ext_vector_type(4)));
typedef float f32x4 __attribute__((ext_vector_type(4)));
typedef unsigned int uint4v __attribute__((ext_vector_type(4)));

#define SEQ 2048
#define DIMM 1024
#define LAMBDA_INIT 0.7008206670670481f

__device__ __forceinline__ unsigned short f2bf(float f) {
  // round-to-nearest-even f32 -> bf16 (no NaNs in our data paths)
  unsigned int u = __float_as_uint(f);
  unsigned int r = u + 0x7fffu + ((u >> 16) & 1u);
  return (unsigned short)(r >> 16);
}
__device__ __forceinline__ float bf2f(unsigned short v) {
  unsigned int u = ((unsigned int)v) << 16;
  return __uint_as_float(u);
}

// async global->LDS, 16B per lane; LDS dst must be the wave-uniform chunk base
// (HW writes lane i at base + i*16).
__device__ __forceinline__ void async16(ushort_t* lds, const ushort_t* g) {
  __builtin_amdgcn_global_load_lds(
      (__attribute__((address_space(1))) void*)(ushort_t*)g,
      (__attribute__((address_space(3))) void*)lds, 16, 0, 0);
}

// ---------------------------------------------------------------------------
// fp32 -> bf16 convert (vectorized). n multiple of 4.
__global__ void cvt_kernel(const float* __restrict__ src, ushort_t* __restrict__ dst, int n) {
  int i = (blockIdx.x * 256 + threadIdx.x) * 4;
  if (i < n) {
    f32x4 v = *(const f32x4*)(src + i);
    ushort4v o;
    o[0] = f2bf(v[0]); o[1] = f2bf(v[1]); o[2] = f2bf(v[2]); o[3] = f2bf(v[3]);
    *(ushort4v*)(dst + i) = o;
  }
}

// ---------------------------------------------------------------------------
// C[M,N] = A[M,K] * Bt[N,K]^T  (bf16 in, fp32 acc, bf16 or fp32 out)
// 128x128 tile, BK=32, 4 waves each 64x64. LDS chunks XOR-swizzled:
// physical 16B-chunk p = k8 ^ ((row>>1)&3) -> async copy stays contiguous,
// frag reads are 2-way (free) conflicts.
template <int OUTF32>
__global__ __launch_bounds__(256, 2) void gemm_bt_kernel(
    const ushort_t* __restrict__ A, const ushort_t* __restrict__ Bt,
    void* __restrict__ Cp, int M, int N, int K) {
  __shared__ __attribute__((aligned(16))) ushort_t As[128 * 32];
  __shared__ __attribute__((aligned(16))) ushort_t Bs[128 * 32];
  const int tid = threadIdx.x;
  const int lane = tid & 63;
  const int wv = tid >> 6;
  const int quad = lane >> 4;
  const int m15 = lane & 15;
  const int wm = (wv >> 1) * 64;
  const int wn = (wv & 1) * 64;
  const int bm = blockIdx.y * 128;
  const int bn = blockIdx.x * 128;

  f32x4 acc[4][4] = {};

  const int srow = lane >> 2;                        // row within 16-row chunk
  const int sk8 = (lane & 3) ^ ((lane >> 3) & 3);    // logical k8 for this lane's slot

  for (int k0 = 0; k0 < K; k0 += 32) {
#pragma unroll
    for (int cc = 0; cc < 2; ++cc) {
      int ch = wv * 2 + cc;
      const ushort_t* ga = A + (size_t)(bm + ch * 16 + srow) * K + k0 + sk8 * 8;
      async16(&As[ch * 512], ga);
      const ushort_t* gb = Bt + (size_t)(bn + ch * 16 + srow) * K + k0 + sk8 * 8;
      async16(&Bs[ch * 512], gb);
    }
    __syncthreads();
    short8 af[4], bfr[4];
#pragma unroll
    for (int t = 0; t < 4; ++t) {
      int ra = wm + t * 16 + m15;
      af[t] = *(const short8*)&As[ra * 32 + (quad ^ ((ra >> 1) & 3)) * 8];
      int rb = wn + t * 16 + m15;
      bfr[t] = *(const short8*)&Bs[rb * 32 + (quad ^ ((rb >> 1) & 3)) * 8];
    }
#pragma unroll
    for (int mt = 0; mt < 4; ++mt)
#pragma unroll
      for (int nt = 0; nt < 4; ++nt)
        acc[mt][nt] = __builtin_amdgcn_mfma_f32_16x16x32_bf16(af[mt], bfr[nt], acc[mt][nt], 0, 0, 0);
    __syncthreads();
  }

#pragma unroll
  for (int mt = 0; mt < 4; ++mt)
#pragma unroll
    for (int nt = 0; nt < 4; ++nt) {
      int col = bn + wn + nt * 16 + m15;
#pragma unroll
      for (int r = 0; r < 4; ++r) {
        int row = bm + wm + mt * 16 + quad * 4 + r;
        if (OUTF32)
          ((float*)Cp)[(size_t)row * N + col] = acc[mt][nt][r];
        else
          ((ushort_t*)Cp)[(size_t)row * N + col] = f2bf(acc[mt][nt][r]);
      }
    }
}

// ---------------------------------------------------------------------------
// Flash attention, causal, per (b, component head h2, 128-row q-tile).
// Q,K: (B*S,1024) bf16, head cols h2*64..+63.  V: head cols (h2>>1)*128..+127.
// Output: O^T bf16 at (B,16,128,SEQ) — coalesced stores, combine reads cols.
__global__ __launch_bounds__(256, 2) void attn_kernel(
    const ushort_t* __restrict__ Q, const ushort_t* __restrict__ Kg,
    const ushort_t* __restrict__ Vg, ushort_t* __restrict__ Op) {
  __shared__ __attribute__((aligned(16))) ushort_t Ks[64 * 64];    // keys x 64, p = c ^ (key&7)
  __shared__ __attribute__((aligned(16))) ushort_t Vt[128 * 64];   // d x keys, p = c ^ ((d^(d>>3))&7)
  __shared__ __attribute__((aligned(16))) ushort_t Pl[4 * 32 * 72]; // per-wave P[q][k], stride 72
  __shared__ float Al[4][32];
  __shared__ float Ll[4][32];

  const int tid = threadIdx.x, lane = tid & 63, wv = tid >> 6;
  const int quad = lane >> 4, m15 = lane & 15;
  const int qt = blockIdx.x, h2 = blockIdx.y, b = blockIdx.z;
  const int qrow0 = qt * 128 + wv * 32;     // this wave's first q (global s)
  const int vcol = (h2 >> 1) * 128;

  // Q fragments live in registers for the whole kernel (A-layout: m=lane&15, k=quad*8+j)
  short8 qf[2][2];
#pragma unroll
  for (int mt = 0; mt < 2; ++mt)
#pragma unroll
    for (int ks = 0; ks < 2; ++ks)
      qf[mt][ks] = *(const short8*)&Q[(size_t)(b * SEQ + qrow0 + mt * 16 + m15) * DIMM +
                                      h2 * 64 + ks * 32 + quad * 8];

  f32x4 oacc[8][2] = {};          // O^T accum: D[m=d][n=q]
  float mrow[2][4], lrow[2][4];
#pragma unroll
  for (int mt = 0; mt < 2; ++mt)
#pragma unroll
    for (int r = 0; r < 4; ++r) { mrow[mt][r] = -__builtin_inff(); lrow[mt][r] = 0.f; }

  const int ktend = qt * 2 + 1;   // keys up to qt*128+127 (block diagonal)

  for (int kt = 0; kt <= ktend; ++kt) {
    // ---- stage K (async, swizzled): chunk = 8 keys, wave does 2 chunks
    {
      int c = (lane & 7) ^ ((lane >> 3) & 7);  // logical k-chunk for this lane's slot
#pragma unroll
      for (int cc = 0; cc < 2; ++cc) {
        int ch = wv * 2 + cc;
        const ushort_t* g = Kg + (size_t)(b * SEQ + kt * 64 + ch * 8 + (lane >> 3)) * DIMM +
                            h2 * 64 + c * 8;
        async16(&Ks[ch * 512], g);
      }
    }
    // ---- stage V transposed (register path, key-pair packed b32 writes)
#pragma unroll
    for (int it = 0; it < 2; ++it) {
      int u = it * 256 + tid;
      int dg = u & 15, kp = u >> 4;
      const ushort_t* g = Vg + (size_t)(b * SEQ + kt * 64 + kp * 2) * DIMM + vcol + dg * 8;
      ushort8v v1 = *(const ushort8v*)g;
      ushort8v v2 = *(const ushort8v*)(g + DIMM);
      int cch = kp >> 2, kb = (kp * 2) & 7;
#pragma unroll
      for (int j = 0; j < 8; ++j) {
        int d = dg * 8 + j;
        int p = cch ^ ((d ^ (d >> 3)) & 7);
        unsigned int w = (unsigned int)v1[j] | ((unsigned int)v2[j] << 16);
        *(unsigned int*)&Vt[d * 64 + p * 8 + kb] = w;
      }
    }
    __syncthreads();

    // ---- S = Q K^T (per wave: 32q x 64keys)
    f32x4 sacc[2][4] = {};
#pragma unroll
    for (int ks = 0; ks < 2; ++ks) {
      short8 kf[4];
#pragma unroll
      for (int nt = 0; nt < 4; ++nt) {
        int kr = nt * 16 + m15;
        kf[nt] = *(const short8*)&Ks[kr * 64 + (((quad + ks * 4) ^ (kr & 7))) * 8];
      }
#pragma unroll
      for (int mt = 0; mt < 2; ++mt)
#pragma unroll
        for (int nt = 0; nt < 4; ++nt)
          sacc[mt][nt] = __builtin_amdgcn_mfma_f32_16x16x32_bf16(qf[mt][ks], kf[nt], sacc[mt][nt], 0, 0, 0);
    }

    // ---- scale, causal mask, online softmax (rows live on 16-lane groups)
    float alpha[2][4];
#pragma unroll
    for (int mt = 0; mt < 2; ++mt) {
#pragma unroll
      for (int r = 0; r < 4; ++r) {
        int qg = qrow0 + mt * 16 + quad * 4 + r;
#pragma unroll
        for (int nt = 0; nt < 4; ++nt) {
          int kg = kt * 64 + nt * 16 + m15;
          float s = sacc[mt][nt][r] * 0.125f;   // 64^-0.5
          sacc[mt][nt][r] = (kg <= qg) ? s : -__builtin_inff();
        }
        float rm = fmaxf(fmaxf(sacc[mt][0][r], sacc[mt][1][r]),
                         fmaxf(sacc[mt][2][r], sacc[mt][3][r]));
        rm = fmaxf(rm, __shfl_xor(rm, 1));
        rm = fmaxf(rm, __shfl_xor(rm, 2));
        rm = fmaxf(rm, __shfl_xor(rm, 4));
        rm = fmaxf(rm, __shfl_xor(rm, 8));
        float mo = mrow[mt][r];
        float mn = fmaxf(mo, rm);              // finite from tile 0 on (diag present)
        float al = __expf(mo - mn);            // first tile: exp(-inf)=0, O==0 anyway
        float ps = 0.f;
#pragma unroll
        for (int nt = 0; nt < 4; ++nt) {
          float p = __expf(sacc[mt][nt][r] - mn);
          sacc[mt][nt][r] = p;
          ps += p;
        }
        ps += __shfl_xor(ps, 1);
        ps += __shfl_xor(ps, 2);
        ps += __shfl_xor(ps, 4);
        ps += __shfl_xor(ps, 8);
        lrow[mt][r] = lrow[mt][r] * al + ps;
        mrow[mt][r] = mn;
        alpha[mt][r] = al;
      }
    }

    // ---- P -> LDS (row-major [q][k], stride 72 keeps 16B-aligned b128 reads)
#pragma unroll
    for (int mt = 0; mt < 2; ++mt)
#pragma unroll
      for (int r = 0; r < 4; ++r) {
        int q = mt * 16 + quad * 4 + r;
#pragma unroll
        for (int nt = 0; nt < 4; ++nt)
          Pl[wv * 2304 + q * 72 + nt * 16 + m15] = f2bf(sacc[mt][nt][r]);
      }
    if (m15 == 0) {
#pragma unroll
      for (int mt = 0; mt < 2; ++mt)
#pragma unroll
        for (int r = 0; r < 4; ++r)
          Al[wv][mt * 16 + quad * 4 + r] = alpha[mt][r];
    }
    // per-column alpha (intra-wave LDS round-trip; in-order DS ops)
    float aq0 = Al[wv][m15], aq1 = Al[wv][16 + m15];
#pragma unroll
    for (int dt = 0; dt < 8; ++dt)
#pragma unroll
      for (int r = 0; r < 4; ++r) { oacc[dt][0][r] *= aq0; oacc[dt][1][r] *= aq1; }

    // ---- O^T += V^T P^T  (A = Vt frags, B = P rows)
#pragma unroll
    for (int ks = 0; ks < 2; ++ks) {
      short8 av[8];
#pragma unroll
      for (int dt = 0; dt < 8; ++dt) {
        int d = dt * 16 + m15;
        int p = (quad + ks * 4) ^ ((d ^ (d >> 3)) & 7);
        av[dt] = *(const short8*)&Vt[d * 64 + p * 8];
      }
#pragma unroll
      for (int qtl = 0; qtl < 2; ++qtl) {
        short8 pf = *(const short8*)&Pl[wv * 2304 + (qtl * 16 + m15) * 72 + ks * 32 + quad * 8];
#pragma unroll
        for (int dt = 0; dt < 8; ++dt)
          oacc[dt][qtl] = __builtin_amdgcn_mfma_f32_16x16x32_bf16(av[dt], pf, oacc[dt][qtl], 0, 0, 0);
      }
    }
    __syncthreads();
  }

  // ---- epilogue: divide by l, store O^T (coalesced along s)
  if (m15 == 0) {
#pragma unroll
    for (int mt = 0; mt < 2; ++mt)
#pragma unroll
      for (int r = 0; r < 4; ++r)
        Ll[wv][mt * 16 + quad * 4 + r] = lrow[mt][r];
  }
  float li0 = 1.f / Ll[wv][m15], li1 = 1.f / Ll[wv][16 + m15];
#pragma unroll
  for (int dt = 0; dt < 8; ++dt)
#pragma unroll
    for (int qtl = 0; qtl < 2; ++qtl) {
      float li = qtl ? li1 : li0;
#pragma unroll
      for (int r = 0; r < 4; ++r) {
        int d = dt * 16 + quad * 4 + r;
        int s = qt * 128 + wv * 32 + qtl * 16 + m15;
        Op[(size_t)((b * 16 + h2) * 128 + d) * SEQ + s] = f2bf(oacc[dt][qtl][r] * li);
      }
    }
}

// ---------------------------------------------------------------------------
// Combine: u = O1 - lam*O2 (per (b,h,s), 128 dims), RMSNorm, *(1-LAMBDA_INIT),
// write (B,S,1024) bf16. Reads O^T layout coalesced along s.
__global__ __launch_bounds__(256) void combine_kernel(
    const ushort_t* __restrict__ Op, const float* __restrict__ lq1,
    const float* __restrict__ lk1, const float* __restrict__ lq2,
    const float* __restrict__ lk2, ushort_t* __restrict__ Oc) {
  const int tid = threadIdx.x;
  const int st = blockIdx.x, h = blockIdx.y, b = blockIdx.z;
  float d1 = 0.f, d2 = 0.f;
  for (int i = 0; i < 64; ++i) { d1 += lq1[i] * lk1[i]; d2 += lq2[i] * lk2[i]; }
  const float lam = __expf(d1) - __expf(d2) + LAMBDA_INIT;

  const int sl = tid & 63, dg = tid >> 6;
  const int s = st * 64 + sl;
  const ushort_t* O1 = Op + (size_t)((b * 16 + 2 * h) * 128 + dg * 32) * SEQ + s;
  const ushort_t* O2 = O1 + (size_t)128 * SEQ;

  float u[32];
  float ssq = 0.f;
#pragma unroll
  for (int i = 0; i < 32; ++i) {
    float a = bf2f(O1[(size_t)i * SEQ]);
    float c = bf2f(O2[(size_t)i * SEQ]);
    float uu = a - lam * c;
    u[i] = uu;
    ssq += uu * uu;
  }
  __shared__ float red[4][64];
  red[dg][sl] = ssq;
  __syncthreads();
  float tot = red[0][sl] + red[1][sl] + red[2][sl] + red[3][sl];
  float scl = rsqrtf(tot * (1.0f / 128.0f) + 1e-5f) * (1.0f - LAMBDA_INIT);

  uint4v ow[4];
#pragma unroll
  for (int w = 0; w < 4; ++w)
#pragma unroll
    for (int j = 0; j < 4; ++j) {
      int i = w * 8 + j * 2;
      ow[w][j] = (unsigned int)f2bf(u[i] * scl) | ((unsigned int)f2bf(u[i + 1] * scl) << 16);
    }
  uint4v* dst = (uint4v*)&Oc[(size_t)(b * SEQ + s) * DIMM + h * 128 + dg * 32];
#pragma unroll
  for (int w = 0; w < 4; ++w) dst[w] = ow[w];
}

// ---------------------------------------------------------------------------
extern "C" void kernel_launch(void* const* d_in, const int* in_sizes, int n_in,
                              void* d_out, int out_size, void* d_ws, size_t ws_size,
                              hipStream_t stream) {
  const float* x   = (const float*)d_in[0];
  const float* Wq  = (const float*)d_in[1];
  const float* Wk  = (const float*)d_in[2];
  const float* Wv  = (const float*)d_in[3];
  const float* Wo  = (const float*)d_in[4];
  const float* lq1 = (const float*)d_in[5];
  const float* lk1 = (const float*)d_in[6];
  const float* lq2 = (const float*)d_in[7];
  const float* lk2 = (const float*)d_in[8];

  char* ws = (char*)d_ws;
  const size_t MB = 1 << 20;
  if (ws_size < 56 * MB) return;  // insufficient scratch; bail cleanly

  ushort_t* xb  = (ushort_t*)(ws + 0);
  ushort_t* Wqb = (ushort_t*)(ws + 8 * MB);
  ushort_t* Wkb = (ushort_t*)(ws + 10 * MB);
  ushort_t* Wvb = (ushort_t*)(ws + 12 * MB);
  ushort_t* Wob = (ushort_t*)(ws + 14 * MB);
  ushort_t* Qb  = (ushort_t*)(ws + 16 * MB);
  ushort_t* Kb  = (ushort_t*)(ws + 24 * MB);
  ushort_t* Vb  = (ushort_t*)(ws + 32 * MB);
  ushort_t* Opb = (ushort_t*)(ws + 40 * MB);  // 16MB
  ushort_t* Oc  = (ushort_t*)(ws + 0);        // reuses xb (dead after QKV gemms)

  // 1) convert
  cvt_kernel<<<4096, 256, 0, stream>>>(x, xb, 4194304);
  cvt_kernel<<<1024, 256, 0, stream>>>(Wq, Wqb, 1048576);
  cvt_kernel<<<1024, 256, 0, stream>>>(Wk, Wkb, 1048576);
  cvt_kernel<<<1024, 256, 0, stream>>>(Wv, Wvb, 1048576);
  cvt_kernel<<<1024, 256, 0, stream>>>(Wo, Wob, 1048576);

  // 2) projections
  dim3 ggrid(8, 32);
  gemm_bt_kernel<0><<<ggrid, 256, 0, stream>>>(xb, Wqb, Qb, 4096, 1024, 1024);
  gemm_bt_kernel<0><<<ggrid, 256, 0, stream>>>(xb, Wkb, Kb, 4096, 1024, 1024);
  gemm_bt_kernel<0><<<ggrid, 256, 0, stream>>>(xb, Wvb, Vb, 4096, 1024, 1024);

  // 3) flash attention (per b, component head, 128-q-tile)
  attn_kernel<<<dim3(16, 16, 2), 256, 0, stream>>>(Qb, Kb, Vb, Opb);

  // 4) combine + RMSNorm
  combine_kernel<<<dim3(32, 8, 2), 256, 0, stream>>>(Opb, lq1, lk1, lq2, lk2, Oc);

  // 5) output projection (fp32 out)
  gemm_bt_kernel<1><<<ggrid, 256, 0, stream>>>(Oc, Wob, (float*)d_out, 4096, 1024, 1024);
}

// Round 3
// 230.714 us; speedup vs baseline: 1.4264x; 1.4264x over previous
//
#include <hip/hip_runtime.h>
#include <hip/hip_bf16.h>

// DiffAttention on MI355X: bf16 MFMA pipeline, round 3.
// Round-2 structure + aliasing fix: P LDS round-trip now stores through a
// short-element vector (TBAA-compatible with the short8 reads) and a compiler
// memory fence sits between the P writes and the PV fragment reads. Round 2
// stored P via uint vectors -> TBAA let the compiler reorder ds_write/ds_read
// (no barrier between, same-wave cross-lane exchange) -> garbage P.
// Workspace layout (bytes):
//   xb   @ 0      8MB   (x bf16, 4096x1024)           [reused later for Oc]
//   Wqb  @ 8M     2MB   Wkb @10M  Wvb @12M  Wob @14M
//   Qb   @16M     8MB   Kb @24M   Vb @32M   (each 4096x1024 bf16; Q pre-scaled)
//   Op   @40M    16MB   (O^T per component head: (B,16,128,S) bf16)
//   Oc   @ 0      8MB   (combined (B,S,1024) bf16, reuses xb region)

typedef unsigned short ushort_t;
typedef short short8 __attribute__((ext_vector_type(8)));
typedef short short4v __attribute__((ext_vector_type(4)));
typedef unsigned short ushort8v __attribute__((ext_vector_type(8)));
typedef unsigned short ushort4v __attribute__((ext_vector_type(4)));
typedef float f32x4 __attribute__((ext_vector_type(4)));
typedef unsigned int uint2v __attribute__((ext_vector_type(2)));
typedef unsigned int uint4v __attribute__((ext_vector_type(4)));

#define SEQ 2048
#define DIMM 1024
#define LAMBDA_INIT 0.7008206670670481f
#define QSCALE 0.18033688011112042f  // 0.125 * log2(e): scores land in log2 domain
#define TAU 16.0f                    // lazy-rescale threshold (log2 units)

__device__ __forceinline__ unsigned short f2bf(float f) {
  unsigned int u = __float_as_uint(f);
  unsigned int r = u + 0x7fffu + ((u >> 16) & 1u);
  return (unsigned short)(r >> 16);
}
__device__ __forceinline__ float bf2f(unsigned short v) {
  unsigned int u = ((unsigned int)v) << 16;
  return __uint_as_float(u);
}

__device__ __forceinline__ void async16(ushort_t* lds, const ushort_t* g) {
  __builtin_amdgcn_global_load_lds(
      (__attribute__((address_space(1))) void*)(ushort_t*)g,
      (__attribute__((address_space(3))) void*)lds, 16, 0, 0);
}

// ---------------------------------------------------------------------------
__global__ void cvt_kernel(const float* __restrict__ src, ushort_t* __restrict__ dst, int n) {
  int i = (blockIdx.x * 256 + threadIdx.x) * 4;
  if (i < n) {
    f32x4 v = *(const f32x4*)(src + i);
    ushort4v o;
    o[0] = f2bf(v[0]); o[1] = f2bf(v[1]); o[2] = f2bf(v[2]); o[3] = f2bf(v[3]);
    *(ushort4v*)(dst + i) = o;
  }
}

// ---------------------------------------------------------------------------
// Fused QKV: C_w[4096,1024] = x * W_w^T, w selected by blockIdx.x>>3.
// Q slice (w==0) pre-scaled by QSCALE. 128x128 tile, BK=32, XOR-swizzled LDS.
__global__ __launch_bounds__(256, 2) void gemm_qkv_kernel(
    const ushort_t* __restrict__ A,
    const ushort_t* __restrict__ Wq, const ushort_t* __restrict__ Wk,
    const ushort_t* __restrict__ Wv,
    ushort_t* __restrict__ Qo, ushort_t* __restrict__ Ko, ushort_t* __restrict__ Vo) {
  __shared__ __attribute__((aligned(16))) ushort_t As[128 * 32];
  __shared__ __attribute__((aligned(16))) ushort_t Bs[128 * 32];
  const int K = 1024, N = 1024;
  const int w = blockIdx.x >> 3;
  const ushort_t* Bt = (w == 0) ? Wq : (w == 1) ? Wk : Wv;
  ushort_t* C = (w == 0) ? Qo : (w == 1) ? Ko : Vo;
  const float oscale = (w == 0) ? QSCALE : 1.0f;
  const int bn = (blockIdx.x & 7) * 128;
  const int bm = blockIdx.y * 128;

  const int tid = threadIdx.x, lane = tid & 63, wv = tid >> 6;
  const int quad = lane >> 4, m15 = lane & 15;
  const int wm = (wv >> 1) * 64, wn = (wv & 1) * 64;

  f32x4 acc[4][4] = {};
  const int srow = lane >> 2;
  const int sk8 = (lane & 3) ^ ((lane >> 3) & 3);

  for (int k0 = 0; k0 < K; k0 += 32) {
#pragma unroll
    for (int cc = 0; cc < 2; ++cc) {
      int ch = wv * 2 + cc;
      async16(&As[ch * 512], A + (size_t)(bm + ch * 16 + srow) * K + k0 + sk8 * 8);
      async16(&Bs[ch * 512], Bt + (size_t)(bn + ch * 16 + srow) * K + k0 + sk8 * 8);
    }
    __syncthreads();
    short8 af[4], bfr[4];
#pragma unroll
    for (int t = 0; t < 4; ++t) {
      int ra = wm + t * 16 + m15;
      af[t] = *(const short8*)&As[ra * 32 + (quad ^ ((ra >> 1) & 3)) * 8];
      int rb = wn + t * 16 + m15;
      bfr[t] = *(const short8*)&Bs[rb * 32 + (quad ^ ((rb >> 1) & 3)) * 8];
    }
#pragma unroll
    for (int mt = 0; mt < 4; ++mt)
#pragma unroll
      for (int nt = 0; nt < 4; ++nt)
        acc[mt][nt] = __builtin_amdgcn_mfma_f32_16x16x32_bf16(af[mt], bfr[nt], acc[mt][nt], 0, 0, 0);
    __syncthreads();
  }

#pragma unroll
  for (int mt = 0; mt < 4; ++mt)
#pragma unroll
    for (int nt = 0; nt < 4; ++nt) {
      int col = bn + wn + nt * 16 + m15;
#pragma unroll
      for (int r = 0; r < 4; ++r) {
        int row = bm + wm + mt * 16 + quad * 4 + r;
        C[(size_t)row * N + col] = f2bf(acc[mt][nt][r] * oscale);
      }
    }
}

// ---------------------------------------------------------------------------
// O-projection: C[4096,1024] f32 = Oc * Wo^T. 128x64 tiles -> 512 blocks (2/CU).
__global__ __launch_bounds__(256, 2) void gemm_bt64_kernel(
    const ushort_t* __restrict__ A, const ushort_t* __restrict__ Bt,
    float* __restrict__ C, int M, int N, int K) {
  __shared__ __attribute__((aligned(16))) ushort_t As[128 * 32];
  __shared__ __attribute__((aligned(16))) ushort_t Bs[64 * 32];
  const int tid = threadIdx.x, lane = tid & 63, wv = tid >> 6;
  const int quad = lane >> 4, m15 = lane & 15;
  const int wm = (wv >> 1) * 64, wn = (wv & 1) * 32;
  const int bm = blockIdx.y * 128, bn = blockIdx.x * 64;
  f32x4 acc[4][2] = {};
  const int srow = lane >> 2;
  const int sk8 = (lane & 3) ^ ((lane >> 3) & 3);

  for (int k0 = 0; k0 < K; k0 += 32) {
    async16(&As[wv * 512], A + (size_t)(bm + wv * 16 + srow) * K + k0 + sk8 * 8);
    async16(&As[(wv + 4) * 512], A + (size_t)(bm + (wv + 4) * 16 + srow) * K + k0 + sk8 * 8);
    async16(&Bs[wv * 512], Bt + (size_t)(bn + wv * 16 + srow) * K + k0 + sk8 * 8);
    __syncthreads();
    short8 af[4], bfr[2];
#pragma unroll
    for (int t = 0; t < 4; ++t) {
      int ra = wm + t * 16 + m15;
      af[t] = *(const short8*)&As[ra * 32 + (quad ^ ((ra >> 1) & 3)) * 8];
    }
#pragma unroll
    for (int t = 0; t < 2; ++t) {
      int rb = wn + t * 16 + m15;
      bfr[t] = *(const short8*)&Bs[rb * 32 + (quad ^ ((rb >> 1) & 3)) * 8];
    }
#pragma unroll
    for (int mt = 0; mt < 4; ++mt)
#pragma unroll
      for (int nt = 0; nt < 2; ++nt)
        acc[mt][nt] = __builtin_amdgcn_mfma_f32_16x16x32_bf16(af[mt], bfr[nt], acc[mt][nt], 0, 0, 0);
    __syncthreads();
  }
#pragma unroll
  for (int mt = 0; mt < 4; ++mt)
#pragma unroll
    for (int nt = 0; nt < 2; ++nt) {
      int col = bn + wn + nt * 16 + m15;
#pragma unroll
      for (int r = 0; r < 4; ++r) {
        int row = bm + wm + mt * 16 + quad * 4 + r;
        C[(size_t)row * N + col] = acc[mt][nt][r];
      }
    }
}

// ---------------------------------------------------------------------------
// Flash attention, causal, per (b, component head h2, 128-row q-tile).
// Heavy-first: bid>>5 -> qt descending. Scores arrive in log2 domain (Q
// pre-scaled). Per-wave lazy scale base mhat (rescale only when wave max
// exceeds mhat+TAU). Row sums via ones-row (d=128) appended to V^T.
// Output O^T bf16 at (B,16,128,SEQ).
__global__ __launch_bounds__(256, 2) void attn_kernel(
    const ushort_t* __restrict__ Q, const ushort_t* __restrict__ Kg,
    const ushort_t* __restrict__ Vg, ushort_t* __restrict__ Op) {
  __shared__ __attribute__((aligned(16))) ushort_t Ks[64 * 64];     // keys x 64, slot = c ^ (key&7)
  __shared__ __attribute__((aligned(16))) ushort_t Vt[144 * 64];    // d x keys (+ones rows)
  __shared__ __attribute__((aligned(16))) ushort_t Pl[4 * 32 * 72]; // per-wave P[q][k]
  __shared__ float Ll[4][32];

  const int tid = threadIdx.x, lane = tid & 63, wv = tid >> 6;
  const int quad = lane >> 4, m15 = lane & 15;
  const int bid = blockIdx.x;
  const int qt = 15 - (bid >> 5);          // heavy blocks dispatch first
  const int h2 = bid & 15, b = (bid >> 4) & 1;
  const int qrow0 = qt * 128 + wv * 32;
  const int vcol = (h2 >> 1) * 128;

  // ones rows for l-via-MFMA: d=128 -> 1.0, d=129..143 -> 0 (written once;
  // first in-loop __syncthreads orders these uint writes vs short8 reads)
  {
    int d = 128 + (tid >> 4);
    int k4 = (tid & 15) * 4;
    unsigned int val = (d == 128) ? 0x3f803f80u : 0u;
    int p = (k4 >> 3) ^ ((d ^ (d >> 3)) & 7);
    *(unsigned int*)&Vt[d * 64 + p * 8 + (k4 & 7)] = val;
    *(unsigned int*)&Vt[d * 64 + p * 8 + (k4 & 7) + 2] = val;
  }

  // Q fragments (B-operand layout), resident all kernel
  short8 qf[2][2];
#pragma unroll
  for (int qtl = 0; qtl < 2; ++qtl)
#pragma unroll
    for (int ks = 0; ks < 2; ++ks)
      qf[qtl][ks] = *(const short8*)&Q[(size_t)(b * SEQ + qrow0 + qtl * 16 + m15) * DIMM +
                                       h2 * 64 + ks * 32 + quad * 8];

  f32x4 oacc[9][2] = {};   // O^T accum; dt=8 is the l row
  float mhat = -3.0e38f;

  const int ktend = qt * 2 + 1;
  for (int kt = 0; kt <= ktend; ++kt) {
    // ---- stage K (async, swizzled)
    {
      int c = (lane & 7) ^ ((lane >> 3) & 7);
#pragma unroll
      for (int cc = 0; cc < 2; ++cc) {
        int ch = wv * 2 + cc;
        const ushort_t* g = Kg + (size_t)(b * SEQ + kt * 64 + ch * 8 + (lane >> 3)) * DIMM +
                            h2 * 64 + c * 8;
        async16(&Ks[ch * 512], g);
      }
    }
    // ---- stage V transposed (register path)
#pragma unroll
    for (int it = 0; it < 2; ++it) {
      int u = it * 256 + tid;
      int dg = u & 15, kp = u >> 4;
      const ushort_t* g = Vg + (size_t)(b * SEQ + kt * 64 + kp * 2) * DIMM + vcol + dg * 8;
      ushort8v v1 = *(const ushort8v*)g;
      ushort8v v2 = *(const ushort8v*)(g + DIMM);
      int cch = kp >> 2, kb = (kp * 2) & 7;
#pragma unroll
      for (int j = 0; j < 8; ++j) {
        int d = dg * 8 + j;
        int p = cch ^ ((d ^ (d >> 3)) & 7);
        unsigned int wd = (unsigned int)v1[j] | ((unsigned int)v2[j] << 16);
        *(unsigned int*)&Vt[d * 64 + p * 8 + kb] = wd;
      }
    }
    __syncthreads();

    if (kt * 64 <= qrow0 + 31) {  // wave has unmasked keys in this tile
      // ---- S^T = K Q^T (D: row=key, col=q -> lanes hold 4 ADJACENT keys)
      f32x4 sacc[4][2] = {};
#pragma unroll
      for (int ks = 0; ks < 2; ++ks) {
        short8 kf[4];
#pragma unroll
        for (int mt = 0; mt < 4; ++mt) {
          int kr = mt * 16 + m15;
          kf[mt] = *(const short8*)&Ks[kr * 64 + (((quad + ks * 4) ^ (kr & 7))) * 8];
        }
#pragma unroll
        for (int mt = 0; mt < 4; ++mt)
#pragma unroll
          for (int qtl = 0; qtl < 2; ++qtl)
            sacc[mt][qtl] = __builtin_amdgcn_mfma_f32_16x16x32_bf16(
                kf[mt], qf[qtl][ks], sacc[mt][qtl], 0, 0, 0);
      }
      if (kt * 64 + 63 > qrow0) {  // diagonal tile only: causal mask
#pragma unroll
        for (int mt = 0; mt < 4; ++mt)
#pragma unroll
          for (int qtl = 0; qtl < 2; ++qtl)
#pragma unroll
            for (int r = 0; r < 4; ++r) {
              int kg = kt * 64 + mt * 16 + quad * 4 + r;
              int qg = qrow0 + qtl * 16 + m15;
              if (kg > qg) sacc[mt][qtl][r] = -3.0e38f;
            }
      }
      // ---- wave max + lazy rescale of scale base
      float lm = -3.0e38f;
#pragma unroll
      for (int mt = 0; mt < 4; ++mt)
#pragma unroll
        for (int qtl = 0; qtl < 2; ++qtl)
          lm = fmaxf(lm, fmaxf(fmaxf(sacc[mt][qtl][0], sacc[mt][qtl][1]),
                               fmaxf(sacc[mt][qtl][2], sacc[mt][qtl][3])));
#pragma unroll
      for (int off = 1; off < 64; off <<= 1) lm = fmaxf(lm, __shfl_xor(lm, off));
      if (lm > mhat + TAU) {
        float al = __builtin_amdgcn_exp2f(mhat - lm);  // first trigger: exp2(-big)=0
        mhat = lm;
#pragma unroll
        for (int dt = 0; dt < 9; ++dt)
#pragma unroll
          for (int qtl = 0; qtl < 2; ++qtl)
#pragma unroll
            for (int r = 0; r < 4; ++r) oacc[dt][qtl][r] *= al;
      }
      // ---- P = exp2(S - mhat); pack pairs (v_perm) and store as short4
      //      (same element type as the short8 reads -> TBAA-safe ordering)
#pragma unroll
      for (int mt = 0; mt < 4; ++mt)
#pragma unroll
        for (int qtl = 0; qtl < 2; ++qtl) {
          unsigned int u0 = __float_as_uint(__builtin_amdgcn_exp2f(sacc[mt][qtl][0] - mhat)) + 0x8000u;
          unsigned int u1 = __float_as_uint(__builtin_amdgcn_exp2f(sacc[mt][qtl][1] - mhat)) + 0x8000u;
          unsigned int u2 = __float_as_uint(__builtin_amdgcn_exp2f(sacc[mt][qtl][2] - mhat)) + 0x8000u;
          unsigned int u3 = __float_as_uint(__builtin_amdgcn_exp2f(sacc[mt][qtl][3] - mhat)) + 0x8000u;
          uint2v pw;
          pw[0] = __builtin_amdgcn_perm(u1, u0, 0x07060302u);
          pw[1] = __builtin_amdgcn_perm(u3, u2, 0x07060302u);
          *(short4v*)&Pl[wv * 2304 + (qtl * 16 + m15) * 72 + mt * 16 + quad * 4] =
              __builtin_bit_cast(short4v, pw);
        }
      // compiler-level fence: forbid hoisting the pf/av ds_reads above the
      // P ds_writes (same-wave cross-lane exchange, no barrier between)
      asm volatile("" ::: "memory");
      // ---- O^T += V^T P^T (dt=8 accumulates row sums l)
#pragma unroll
      for (int ks = 0; ks < 2; ++ks) {
        short8 av[9];
#pragma unroll
        for (int dt = 0; dt < 9; ++dt) {
          int d = dt * 16 + m15;
          int p = (quad + ks * 4) ^ ((d ^ (d >> 3)) & 7);
          av[dt] = *(const short8*)&Vt[d * 64 + p * 8];
        }
#pragma unroll
        for (int qtl = 0; qtl < 2; ++qtl) {
          short8 pf = *(const short8*)&Pl[wv * 2304 + (qtl * 16 + m15) * 72 + ks * 32 + quad * 8];
#pragma unroll
          for (int dt = 0; dt < 9; ++dt)
            oacc[dt][qtl] = __builtin_amdgcn_mfma_f32_16x16x32_bf16(av[dt], pf, oacc[dt][qtl], 0, 0, 0);
        }
      }
    }
    __syncthreads();
  }

  // ---- epilogue: l sits at dt=8, MFMA row 0 (quad==0, r==0)
  if (quad == 0) {
    Ll[wv][m15] = oacc[8][0][0];
    Ll[wv][16 + m15] = oacc[8][1][0];
  }
  asm volatile("" ::: "memory");
  float li0 = 1.0f / Ll[wv][m15];
  float li1 = 1.0f / Ll[wv][16 + m15];
#pragma unroll
  for (int dt = 0; dt < 8; ++dt)
#pragma unroll
    for (int qtl = 0; qtl < 2; ++qtl) {
      float li = qtl ? li1 : li0;
#pragma unroll
      for (int r = 0; r < 4; ++r) {
        int d = dt * 16 + quad * 4 + r;
        int s = qt * 128 + wv * 32 + qtl * 16 + m15;
        Op[(size_t)((b * 16 + h2) * 128 + d) * SEQ + s] = f2bf(oacc[dt][qtl][r] * li);
      }
    }
}

// ---------------------------------------------------------------------------
__global__ __launch_bounds__(256) void combine_kernel(
    const ushort_t* __restrict__ Op, const float* __restrict__ lq1,
    const float* __restrict__ lk1, const float* __restrict__ lq2,
    const float* __restrict__ lk2, ushort_t* __restrict__ Oc) {
  const int tid = threadIdx.x;
  const int st = blockIdx.x, h = blockIdx.y, b = blockIdx.z;
  float d1 = 0.f, d2 = 0.f;
  for (int i = 0; i < 64; ++i) { d1 += lq1[i] * lk1[i]; d2 += lq2[i] * lk2[i]; }
  const float lam = __expf(d1) - __expf(d2) + LAMBDA_INIT;

  const int sl = tid & 63, dg = tid >> 6;
  const int s = st * 64 + sl;
  const ushort_t* O1 = Op + (size_t)((b * 16 + 2 * h) * 128 + dg * 32) * SEQ + s;
  const ushort_t* O2 = O1 + (size_t)128 * SEQ;

  float u[32];
  float ssq = 0.f;
#pragma unroll
  for (int i = 0; i < 32; ++i) {
    float a = bf2f(O1[(size_t)i * SEQ]);
    float c = bf2f(O2[(size_t)i * SEQ]);
    float uu = a - lam * c;
    u[i] = uu;
    ssq += uu * uu;
  }
  __shared__ float red[4][64];
  red[dg][sl] = ssq;
  __syncthreads();
  float tot = red[0][sl] + red[1][sl] + red[2][sl] + red[3][sl];
  float scl = rsqrtf(tot * (1.0f / 128.0f) + 1e-5f) * (1.0f - LAMBDA_INIT);

  uint4v ow[4];
#pragma unroll
  for (int w = 0; w < 4; ++w)
#pragma unroll
    for (int j = 0; j < 4; ++j) {
      int i = w * 8 + j * 2;
      ow[w][j] = (unsigned int)f2bf(u[i] * scl) | ((unsigned int)f2bf(u[i + 1] * scl) << 16);
    }
  uint4v* dst = (uint4v*)&Oc[(size_t)(b * SEQ + s) * DIMM + h * 128 + dg * 32];
#pragma unroll
  for (int w = 0; w < 4; ++w) dst[w] = ow[w];
}

// ---------------------------------------------------------------------------
extern "C" void kernel_launch(void* const* d_in, const int* in_sizes, int n_in,
                              void* d_out, int out_size, void* d_ws, size_t ws_size,
                              hipStream_t stream) {
  const float* x   = (const float*)d_in[0];
  const float* Wq  = (const float*)d_in[1];
  const float* Wk  = (const float*)d_in[2];
  const float* Wv  = (const float*)d_in[3];
  const float* Wo  = (const float*)d_in[4];
  const float* lq1 = (const float*)d_in[5];
  const float* lk1 = (const float*)d_in[6];
  const float* lq2 = (const float*)d_in[7];
  const float* lk2 = (const float*)d_in[8];

  char* ws = (char*)d_ws;
  const size_t MB = 1 << 20;
  if (ws_size < 56 * MB) return;

  ushort_t* xb  = (ushort_t*)(ws + 0);
  ushort_t* Wqb = (ushort_t*)(ws + 8 * MB);
  ushort_t* Wkb = (ushort_t*)(ws + 10 * MB);
  ushort_t* Wvb = (ushort_t*)(ws + 12 * MB);
  ushort_t* Wob = (ushort_t*)(ws + 14 * MB);
  ushort_t* Qb  = (ushort_t*)(ws + 16 * MB);
  ushort_t* Kb  = (ushort_t*)(ws + 24 * MB);
  ushort_t* Vb  = (ushort_t*)(ws + 32 * MB);
  ushort_t* Opb = (ushort_t*)(ws + 40 * MB);
  ushort_t* Oc  = (ushort_t*)(ws + 0);   // reuses xb (dead after QKV gemm)

  cvt_kernel<<<4096, 256, 0, stream>>>(x, xb, 4194304);
  cvt_kernel<<<1024, 256, 0, stream>>>(Wq, Wqb, 1048576);
  cvt_kernel<<<1024, 256, 0, stream>>>(Wk, Wkb, 1048576);
  cvt_kernel<<<1024, 256, 0, stream>>>(Wv, Wvb, 1048576);
  cvt_kernel<<<1024, 256, 0, stream>>>(Wo, Wob, 1048576);

  gemm_qkv_kernel<<<dim3(24, 32), 256, 0, stream>>>(xb, Wqb, Wkb, Wvb, Qb, Kb, Vb);

  attn_kernel<<<512, 256, 0, stream>>>(Qb, Kb, Vb, Opb);

  combine_kernel<<<dim3(32, 8, 2), 256, 0, stream>>>(Opb, lq1, lk1, lq2, lk2, Oc);

  gemm_bt64_kernel<<<dim3(16, 32), 256, 0, stream>>>(Oc, Wob, (float*)d_out, 4096, 1024, 1024);
}